// Round 11
// baseline (105.702 us; speedup 1.0000x reference)
//
#include <hip/hip_runtime.h>

#define BN_EPS 1e-5f
#define WW 56
#define HWSZ 3136      // 56*56
#define NB 32
#define CIN 240
#define MID 60
#define MIDG 20        // mid channels per group
#define COUT 240
#define COUTG 80

// ======== K1: grouped conv1x1 (240->60, G=3) + BN1 + ReLU -> t1 ========
// Thread = (position quad, ci-chunk). chunk = lane&3 covers 20 of the 80
// input channels; partial acc[20] (all out-channels of the group) is reduced
// across the 4 chunk-lanes with a quad shfl_xor butterfly. kB's measured-good
// profile (20 loads : 1600 FMAs per thread) at 1176 blocks.
// NOTE: plain __launch_bounds__(256). (256,4) caps VGPR at 64 -> acc[20]
// (80 VGPR) spills to scratch (R9: 146us, 196MB scratch writes). R1 precedent:
// plain bound gives VGPR_Count=128 for the same accumulator, no spill.
__global__ __launch_bounds__(256) void k1_conv1_bn_relu(
        const float* __restrict__ x, const float* __restrict__ w1,
        const float* __restrict__ g1, const float* __restrict__ b1,
        const float* __restrict__ m1, const float* __restrict__ v1,
        float* __restrict__ t1) {
    __shared__ float wT[3 * 80 * MIDG];   // [g][ci][co], scale-folded; 19.2 KB
    __shared__ float sh1L[MID];
    const int tid = threadIdx.x;
    for (int i = tid; i < MID * 80; i += 256) {
        int co_glob = i / 80;             // w1 row
        int ci = i % 80;
        int gg = co_glob / MIDG, co = co_glob % MIDG;
        float s1v = g1[co_glob] * rsqrtf(v1[co_glob] + BN_EPS);
        wT[(gg * 80 + ci) * MIDG + co] = w1[i] * s1v;
    }
    if (tid < MID) {
        float s1v = g1[tid] * rsqrtf(v1[tid] + BN_EPS);
        sh1L[tid] = b1[tid] - m1[tid] * s1v;
    }
    __syncthreads();

    const int item  = blockIdx.x * 256 + tid;   // < 32*3*784*4 = 301056
    const int chunk = item & 3;                 // lane&3: which 20 input chans
    const int pg    = item >> 2;                // position index < 75264
    const int p4    = pg % 784;
    const int bg    = pg / 784;
    const int b = bg / 3, g = bg % 3;
    const int pos = p4 * 4;

    const float* xp = x + ((size_t)(b * CIN + g * 80 + chunk * 20)) * HWSZ + pos;
    const float* wbase = wT + (g * 80 + chunk * 20) * MIDG;

    float4 acc[MIDG];
#pragma unroll
    for (int j = 0; j < MIDG; j++) acc[j] = make_float4(0.f, 0.f, 0.f, 0.f);

#pragma unroll 4
    for (int ci = 0; ci < 20; ci++) {
        float4 xv = *(const float4*)(xp + (size_t)ci * HWSZ);
        const float4* wrow = (const float4*)(wbase + ci * MIDG);
#pragma unroll
        for (int k4 = 0; k4 < 5; k4++) {
            float4 wv = wrow[k4];
            acc[k4 * 4 + 0].x += wv.x * xv.x; acc[k4 * 4 + 0].y += wv.x * xv.y;
            acc[k4 * 4 + 0].z += wv.x * xv.z; acc[k4 * 4 + 0].w += wv.x * xv.w;
            acc[k4 * 4 + 1].x += wv.y * xv.x; acc[k4 * 4 + 1].y += wv.y * xv.y;
            acc[k4 * 4 + 1].z += wv.y * xv.z; acc[k4 * 4 + 1].w += wv.y * xv.w;
            acc[k4 * 4 + 2].x += wv.z * xv.x; acc[k4 * 4 + 2].y += wv.z * xv.y;
            acc[k4 * 4 + 2].z += wv.z * xv.z; acc[k4 * 4 + 2].w += wv.z * xv.w;
            acc[k4 * 4 + 3].x += wv.w * xv.x; acc[k4 * 4 + 3].y += wv.w * xv.y;
            acc[k4 * 4 + 3].z += wv.w * xv.z; acc[k4 * 4 + 3].w += wv.w * xv.w;
        }
    }

    // ---- butterfly-reduce partial sums across the 4 chunk-lanes (quad DPP) ----
#pragma unroll
    for (int j = 0; j < MIDG; j++) {
        acc[j].x += __shfl_xor(acc[j].x, 1); acc[j].y += __shfl_xor(acc[j].y, 1);
        acc[j].z += __shfl_xor(acc[j].z, 1); acc[j].w += __shfl_xor(acc[j].w, 1);
        acc[j].x += __shfl_xor(acc[j].x, 2); acc[j].y += __shfl_xor(acc[j].y, 2);
        acc[j].z += __shfl_xor(acc[j].z, 2); acc[j].w += __shfl_xor(acc[j].w, 2);
    }

    // ---- each chunk-lane stores 5 of the 20 out-channels (static indexing) ----
#pragma unroll
    for (int j = 0; j < MIDG; j++) {
        if (j / 5 == chunk) {               // j/5 compile-time; exec-masked store
            int ch = g * MIDG + j;
            float sf = sh1L[ch];
            float4 o;
            o.x = fmaxf(acc[j].x + sf, 0.f);
            o.y = fmaxf(acc[j].y + sf, 0.f);
            o.z = fmaxf(acc[j].z + sf, 0.f);
            o.w = fmaxf(acc[j].w + sf, 0.f);
            *(float4*)(t1 + ((size_t)(b * MID + ch)) * HWSZ + pos) = o;
        }
    }
}

// ======== K2: depthwise 3x3 (pad 1) + BN2 -> t2, written channel-shuffled ====
__global__ __launch_bounds__(256) void k2_dw_bn_shuffle(
        const float* __restrict__ t1, const float* __restrict__ w2,
        const float* __restrict__ g2, const float* __restrict__ b2,
        const float* __restrict__ m2, const float* __restrict__ v2,
        float* __restrict__ t2) {
    const int item = blockIdx.x * 256 + threadIdx.x;   // < 1505280
    const unsigned bc = (unsigned)item / 784u;
    const unsigned p4 = (unsigned)item % 784u;
    const unsigned c = bc % (unsigned)MID;
    const unsigned b = bc / (unsigned)MID;
    const int pos = (int)p4 * 4;
    const int h = pos / WW;
    const int w = pos % WW;

    const float inv = g2[c] * rsqrtf(v2[c] + BN_EPS);
    const float sf  = b2[c] - m2[c] * inv;
    const float* base = t1 + (size_t)bc * HWSZ;
    float kf[9];
#pragma unroll
    for (int i = 0; i < 9; i++) kf[i] = w2[c * 9 + i] * inv;

    float acc0 = 0.f, acc1 = 0.f, acc2 = 0.f, acc3 = 0.f;
#pragma unroll
    for (int dy = -1; dy <= 1; dy++) {
        int rr = h + dy;
        if (rr < 0 || rr >= 56) continue;
        const float* row = base + rr * WW + w;
        float4 mid4 = *(const float4*)row;
        float v0 = (w > 0) ? row[-1] : 0.f;
        float v5 = (w + 4 < WW) ? row[4] : 0.f;
        const float k0 = kf[(dy + 1) * 3 + 0];
        const float k1 = kf[(dy + 1) * 3 + 1];
        const float k2 = kf[(dy + 1) * 3 + 2];
        acc0 += k0 * v0     + k1 * mid4.x + k2 * mid4.y;
        acc1 += k0 * mid4.x + k1 * mid4.y + k2 * mid4.z;
        acc2 += k0 * mid4.y + k1 * mid4.z + k2 * mid4.w;
        acc3 += k0 * mid4.z + k1 * mid4.w + k2 * v5;
    }

    float4 o;
    o.x = acc0 + sf; o.y = acc1 + sf; o.z = acc2 + sf; o.w = acc3 + sf;
    const unsigned jj = (c % 20u) * 3u + c / 20u;      // shuffled channel index
    *(float4*)(t2 + ((size_t)(b * MID + jj)) * HWSZ + pos) = o;
}

// ======== K3: grouped conv1x1 (60->240, inputs pre-shuffled) + BN3 + ReLU
//          + residual add ========
__global__ __launch_bounds__(256) void kB_conv3_res(
        const float* __restrict__ t2, const float* __restrict__ w3,
        const float* __restrict__ g3, const float* __restrict__ b3,
        const float* __restrict__ m3, const float* __restrict__ v3,
        const float* __restrict__ x, float* __restrict__ out) {
    __shared__ float wT[3 * MIDG * COUTG];  // [g][ci][cg] : 4800 floats
    __shared__ float s3[COUT], sh3[COUT];
    const int tid = threadIdx.x;
    for (int i = tid; i < 3 * MIDG * COUTG; i += 256) {
        int co_glob = i / MIDG;
        int ci = i % MIDG;
        int gg = co_glob / COUTG;
        int cg = co_glob % COUTG;
        wT[(gg * MIDG + ci) * COUTG + cg] = w3[i];
    }
    if (tid < COUT) {
        float inv = g3[tid] * rsqrtf(v3[tid] + BN_EPS);
        s3[tid] = inv;
        sh3[tid] = b3[tid] - m3[tid] * inv;
    }
    __syncthreads();

    const int item = blockIdx.x * 256 + tid;  // < 301056
    const unsigned q  = (unsigned)item & 3u;
    const unsigned pg = (unsigned)item >> 2;
    const unsigned p4 = pg % 784u;
    const unsigned bg = pg / 784u;
    const unsigned b = bg / 3u, g = bg % 3u;
    const int pos = (int)p4 * 4;

    float4 acc[MIDG];
#pragma unroll
    for (int c = 0; c < MIDG; c++) acc[c] = make_float4(0.f, 0.f, 0.f, 0.f);

    const float4* wl4 = (const float4*)wT;
#pragma unroll 4
    for (int ci = 0; ci < MIDG; ci++) {
        int csh = (int)g * MIDG + ci;
        float4 xv = *(const float4*)(t2 + ((size_t)(b * MID + csh)) * HWSZ + pos);
        int wbase = (csh * COUTG + q * MIDG) / 4;
#pragma unroll
        for (int k4 = 0; k4 < 5; k4++) {
            float4 wv = wl4[wbase + k4];
            acc[k4 * 4 + 0].x += wv.x * xv.x; acc[k4 * 4 + 0].y += wv.x * xv.y;
            acc[k4 * 4 + 0].z += wv.x * xv.z; acc[k4 * 4 + 0].w += wv.x * xv.w;
            acc[k4 * 4 + 1].x += wv.y * xv.x; acc[k4 * 4 + 1].y += wv.y * xv.y;
            acc[k4 * 4 + 1].z += wv.y * xv.z; acc[k4 * 4 + 1].w += wv.y * xv.w;
            acc[k4 * 4 + 2].x += wv.z * xv.x; acc[k4 * 4 + 2].y += wv.z * xv.y;
            acc[k4 * 4 + 2].z += wv.z * xv.z; acc[k4 * 4 + 2].w += wv.z * xv.w;
            acc[k4 * 4 + 3].x += wv.w * xv.x; acc[k4 * 4 + 3].y += wv.w * xv.y;
            acc[k4 * 4 + 3].z += wv.w * xv.z; acc[k4 * 4 + 3].w += wv.w * xv.w;
        }
    }

#pragma unroll
    for (int co = 0; co < MIDG; co++) {
        int cg = (int)g * COUTG + (int)q * MIDG + co;
        float sc = s3[cg], sf = sh3[cg];
        float4 xr = *(const float4*)(x + ((size_t)(b * CIN + cg)) * HWSZ + pos);
        float4 o;
        o.x = fmaxf(acc[co].x * sc + sf, 0.f) + xr.x;
        o.y = fmaxf(acc[co].y * sc + sf, 0.f) + xr.y;
        o.z = fmaxf(acc[co].z * sc + sf, 0.f) + xr.z;
        o.w = fmaxf(acc[co].w * sc + sf, 0.f) + xr.w;
        *(float4*)(out + ((size_t)(b * CIN + cg)) * HWSZ + pos) = o;
    }
}

extern "C" void kernel_launch(void* const* d_in, const int* in_sizes, int n_in,
                              void* d_out, int out_size, void* d_ws, size_t ws_size,
                              hipStream_t stream) {
    const float* x  = (const float*)d_in[0];
    const float* w1 = (const float*)d_in[1];
    const float* g1 = (const float*)d_in[2];
    const float* b1 = (const float*)d_in[3];
    const float* m1 = (const float*)d_in[4];
    const float* v1 = (const float*)d_in[5];
    const float* w2 = (const float*)d_in[6];
    const float* g2 = (const float*)d_in[7];
    const float* b2 = (const float*)d_in[8];
    const float* m2 = (const float*)d_in[9];
    const float* v2 = (const float*)d_in[10];
    const float* w3 = (const float*)d_in[11];
    const float* g3 = (const float*)d_in[12];
    const float* b3 = (const float*)d_in[13];
    const float* m3 = (const float*)d_in[14];
    const float* v3 = (const float*)d_in[15];
    float* out = (float*)d_out;

    float* t1 = (float*)d_ws;                          // 24 MB
    float* t2 = t1 + (size_t)NB * MID * HWSZ;          // 24 MB (shuffled)

    // K1: 301056 threads / 256 = 1176 blocks
    k1_conv1_bn_relu<<<1176, 256, 0, stream>>>(x, w1, g1, b1, m1, v1, t1);
    // K2: 1505280 / 256 = 5880 blocks
    k2_dw_bn_shuffle<<<5880, 256, 0, stream>>>(t1, w2, g2, b2, m2, v2, t2);
    // K3: 301056 / 256 = 1176 blocks
    kB_conv3_res<<<1176, 256, 0, stream>>>(t2, w3, g3, b3, m3, v3, x, out);
}

// Round 12
// 91.742 us; speedup vs baseline: 1.1522x; 1.1522x over previous
//
#include <hip/hip_runtime.h>

#define BN_EPS 1e-5f
#define WW 56
#define HWSZ 3136      // 56*56
#define NB 32
#define CIN 240
#define MID 60
#define MIDG 20        // mid channels per group
#define COUT 240
#define COUTG 80

// ======== K1: grouped conv1x1 (240->60, G=3) + BN1 + ReLU -> t1 ========
// SCALAR positions: one thread = one spatial position, all 20 out-channels of
// its group. acc[20] is 20 scalar VGPRs (vs 80 for the float4 variants that
// all plateaued at ~62us with 4 waves/SIMD). x loads are 8 independent dwords
// per batch (wave = 256B contiguous per inst); weights are wave-uniform LDS
// broadcasts (free); BN scale folded into staged weights. No shuffles, no
// splits, no barriers in the hot loop.
__global__ __launch_bounds__(256) void k1_conv1_bn_relu(
        const float* __restrict__ x, const float* __restrict__ w1,
        const float* __restrict__ g1, const float* __restrict__ b1,
        const float* __restrict__ m1, const float* __restrict__ v1,
        float* __restrict__ t1) {
    __shared__ float wT[3 * 80 * MIDG];   // [g][ci][co], scale-folded; 19.2 KB
    __shared__ float sh1L[MID];
    const int tid = threadIdx.x;
    for (int i = tid; i < MID * 80; i += 256) {
        int co_glob = i / 80;             // w1 row
        int ci = i % 80;
        int gg = co_glob / MIDG, co = co_glob % MIDG;
        float s1v = g1[co_glob] * rsqrtf(v1[co_glob] + BN_EPS);
        wT[(gg * 80 + ci) * MIDG + co] = w1[i] * s1v;
    }
    if (tid < MID) {
        float s1v = g1[tid] * rsqrtf(v1[tid] + BN_EPS);
        sh1L[tid] = b1[tid] - m1[tid] * s1v;
    }
    __syncthreads();

    const int item = blockIdx.x * 256 + tid;   // < 96*3136 = 301056
    const int p    = item % HWSZ;              // scalar position
    const int bg   = item / HWSZ;
    const int b = bg / 3, g = bg % 3;

    const float* xp = x + ((size_t)(b * CIN + g * 80)) * HWSZ + p;
    const float* wg = wT + (g * 80) * MIDG;

    float acc[MIDG];
#pragma unroll
    for (int k = 0; k < MIDG; k++) acc[k] = 0.f;

    for (int c8 = 0; c8 < 10; ++c8) {         // 8 input channels per batch
        float xv[8];
#pragma unroll
        for (int j = 0; j < 8; j++)
            xv[j] = xp[(size_t)(c8 * 8 + j) * HWSZ];   // 8 loads in flight
#pragma unroll
        for (int j = 0; j < 8; j++) {
            const float4* wrow = (const float4*)(wg + (c8 * 8 + j) * MIDG);
#pragma unroll
            for (int k4 = 0; k4 < 5; k4++) {
                float4 wv = wrow[k4];                   // LDS broadcast (b128)
                acc[k4 * 4 + 0] += wv.x * xv[j];
                acc[k4 * 4 + 1] += wv.y * xv[j];
                acc[k4 * 4 + 2] += wv.z * xv[j];
                acc[k4 * 4 + 3] += wv.w * xv[j];
            }
        }
    }

#pragma unroll
    for (int k = 0; k < MIDG; k++) {
        int ch = g * MIDG + k;
        float o = fmaxf(acc[k] + sh1L[ch], 0.f);
        t1[((size_t)(b * MID + ch)) * HWSZ + p] = o;   // wave = 256B per store
    }
}

// ======== K2: depthwise 3x3 (pad 1) + BN2 -> t2, written channel-shuffled ====
__global__ __launch_bounds__(256) void k2_dw_bn_shuffle(
        const float* __restrict__ t1, const float* __restrict__ w2,
        const float* __restrict__ g2, const float* __restrict__ b2,
        const float* __restrict__ m2, const float* __restrict__ v2,
        float* __restrict__ t2) {
    const int item = blockIdx.x * 256 + threadIdx.x;   // < 1505280
    const unsigned bc = (unsigned)item / 784u;
    const unsigned p4 = (unsigned)item % 784u;
    const unsigned c = bc % (unsigned)MID;
    const unsigned b = bc / (unsigned)MID;
    const int pos = (int)p4 * 4;
    const int h = pos / WW;
    const int w = pos % WW;

    const float inv = g2[c] * rsqrtf(v2[c] + BN_EPS);
    const float sf  = b2[c] - m2[c] * inv;
    const float* base = t1 + (size_t)bc * HWSZ;
    float kf[9];
#pragma unroll
    for (int i = 0; i < 9; i++) kf[i] = w2[c * 9 + i] * inv;

    float acc0 = 0.f, acc1 = 0.f, acc2 = 0.f, acc3 = 0.f;
#pragma unroll
    for (int dy = -1; dy <= 1; dy++) {
        int rr = h + dy;
        if (rr < 0 || rr >= 56) continue;
        const float* row = base + rr * WW + w;
        float4 mid4 = *(const float4*)row;
        float v0 = (w > 0) ? row[-1] : 0.f;
        float v5 = (w + 4 < WW) ? row[4] : 0.f;
        const float k0 = kf[(dy + 1) * 3 + 0];
        const float k1 = kf[(dy + 1) * 3 + 1];
        const float k2 = kf[(dy + 1) * 3 + 2];
        acc0 += k0 * v0     + k1 * mid4.x + k2 * mid4.y;
        acc1 += k0 * mid4.x + k1 * mid4.y + k2 * mid4.z;
        acc2 += k0 * mid4.y + k1 * mid4.z + k2 * mid4.w;
        acc3 += k0 * mid4.z + k1 * mid4.w + k2 * v5;
    }

    float4 o;
    o.x = acc0 + sf; o.y = acc1 + sf; o.z = acc2 + sf; o.w = acc3 + sf;
    const unsigned jj = (c % 20u) * 3u + c / 20u;      // shuffled channel index
    *(float4*)(t2 + ((size_t)(b * MID + jj)) * HWSZ + pos) = o;
}

// ======== K3: grouped conv1x1 (60->240, inputs pre-shuffled) + BN3 + ReLU
//          + residual add ========
__global__ __launch_bounds__(256) void kB_conv3_res(
        const float* __restrict__ t2, const float* __restrict__ w3,
        const float* __restrict__ g3, const float* __restrict__ b3,
        const float* __restrict__ m3, const float* __restrict__ v3,
        const float* __restrict__ x, float* __restrict__ out) {
    __shared__ float wT[3 * MIDG * COUTG];  // [g][ci][cg] : 4800 floats
    __shared__ float s3[COUT], sh3[COUT];
    const int tid = threadIdx.x;
    for (int i = tid; i < 3 * MIDG * COUTG; i += 256) {
        int co_glob = i / MIDG;
        int ci = i % MIDG;
        int gg = co_glob / COUTG;
        int cg = co_glob % COUTG;
        wT[(gg * MIDG + ci) * COUTG + cg] = w3[i];
    }
    if (tid < COUT) {
        float inv = g3[tid] * rsqrtf(v3[tid] + BN_EPS);
        s3[tid] = inv;
        sh3[tid] = b3[tid] - m3[tid] * inv;
    }
    __syncthreads();

    const int item = blockIdx.x * 256 + tid;  // < 301056
    const unsigned q  = (unsigned)item & 3u;
    const unsigned pg = (unsigned)item >> 2;
    const unsigned p4 = pg % 784u;
    const unsigned bg = pg / 784u;
    const unsigned b = bg / 3u, g = bg % 3u;
    const int pos = (int)p4 * 4;

    float4 acc[MIDG];
#pragma unroll
    for (int c = 0; c < MIDG; c++) acc[c] = make_float4(0.f, 0.f, 0.f, 0.f);

    const float4* wl4 = (const float4*)wT;
#pragma unroll 4
    for (int ci = 0; ci < MIDG; ci++) {
        int csh = (int)g * MIDG + ci;
        float4 xv = *(const float4*)(t2 + ((size_t)(b * MID + csh)) * HWSZ + pos);
        int wbase = (csh * COUTG + q * MIDG) / 4;
#pragma unroll
        for (int k4 = 0; k4 < 5; k4++) {
            float4 wv = wl4[wbase + k4];
            acc[k4 * 4 + 0].x += wv.x * xv.x; acc[k4 * 4 + 0].y += wv.x * xv.y;
            acc[k4 * 4 + 0].z += wv.x * xv.z; acc[k4 * 4 + 0].w += wv.x * xv.w;
            acc[k4 * 4 + 1].x += wv.y * xv.x; acc[k4 * 4 + 1].y += wv.y * xv.y;
            acc[k4 * 4 + 1].z += wv.y * xv.z; acc[k4 * 4 + 1].w += wv.y * xv.w;
            acc[k4 * 4 + 2].x += wv.z * xv.x; acc[k4 * 4 + 2].y += wv.z * xv.y;
            acc[k4 * 4 + 2].z += wv.z * xv.z; acc[k4 * 4 + 2].w += wv.z * xv.w;
            acc[k4 * 4 + 3].x += wv.w * xv.x; acc[k4 * 4 + 3].y += wv.w * xv.y;
            acc[k4 * 4 + 3].z += wv.w * xv.z; acc[k4 * 4 + 3].w += wv.w * xv.w;
        }
    }

#pragma unroll
    for (int co = 0; co < MIDG; co++) {
        int cg = (int)g * COUTG + (int)q * MIDG + co;
        float sc = s3[cg], sf = sh3[cg];
        float4 xr = *(const float4*)(x + ((size_t)(b * CIN + cg)) * HWSZ + pos);
        float4 o;
        o.x = fmaxf(acc[co].x * sc + sf, 0.f) + xr.x;
        o.y = fmaxf(acc[co].y * sc + sf, 0.f) + xr.y;
        o.z = fmaxf(acc[co].z * sc + sf, 0.f) + xr.z;
        o.w = fmaxf(acc[co].w * sc + sf, 0.f) + xr.w;
        *(float4*)(out + ((size_t)(b * CIN + cg)) * HWSZ + pos) = o;
    }
}

extern "C" void kernel_launch(void* const* d_in, const int* in_sizes, int n_in,
                              void* d_out, int out_size, void* d_ws, size_t ws_size,
                              hipStream_t stream) {
    const float* x  = (const float*)d_in[0];
    const float* w1 = (const float*)d_in[1];
    const float* g1 = (const float*)d_in[2];
    const float* b1 = (const float*)d_in[3];
    const float* m1 = (const float*)d_in[4];
    const float* v1 = (const float*)d_in[5];
    const float* w2 = (const float*)d_in[6];
    const float* g2 = (const float*)d_in[7];
    const float* b2 = (const float*)d_in[8];
    const float* m2 = (const float*)d_in[9];
    const float* v2 = (const float*)d_in[10];
    const float* w3 = (const float*)d_in[11];
    const float* g3 = (const float*)d_in[12];
    const float* b3 = (const float*)d_in[13];
    const float* m3 = (const float*)d_in[14];
    const float* v3 = (const float*)d_in[15];
    float* out = (float*)d_out;

    float* t1 = (float*)d_ws;                          // 24 MB
    float* t2 = t1 + (size_t)NB * MID * HWSZ;          // 24 MB (shuffled)

    // K1: 301056 threads / 256 = 1176 blocks
    k1_conv1_bn_relu<<<1176, 256, 0, stream>>>(x, w1, g1, b1, m1, v1, t1);
    // K2: 1505280 / 256 = 5880 blocks
    k2_dw_bn_shuffle<<<5880, 256, 0, stream>>>(t1, w2, g2, b2, m2, v2, t2);
    // K3: 301056 / 256 = 1176 blocks
    kB_conv3_res<<<1176, 256, 0, stream>>>(t2, w3, g3, b3, m3, v3, x, out);
}